// Round 10
// baseline (1380.382 us; speedup 1.0000x reference)
//
#include <hip/hip_runtime.h>
#include <hip/hip_bf16.h>
#include <cstdint>
#include <cstddef>

// Round 10: big-3 GEMMs moved to gemm_256 — the m201-style 256x256 8-phase
// schedule: BK=64, 8 waves, 128KiB double-buffered LDS, counted vmcnt(6)
// (never 0 in steady state), per-phase {ds_read || stage-issue || 16 MFMA}
// interleave, setprio around MFMA, exact XOR swizzle (round-9-proven, 0
// bank conflicts). Staging stagger proven WAR/RAW-safe (see session notes).
// Projections stay on round-9 gemm_bt (BK=64, 833 TF verified).

typedef __bf16 bf16;
typedef __bf16 bf16x4 __attribute__((ext_vector_type(4)));
typedef __bf16 bf16x8 __attribute__((ext_vector_type(8)));
typedef float  f32x4  __attribute__((ext_vector_type(4)));

#define BATCH 16
#define NQ    576
#define MM    1024
#define HID   4096
#define HEADS 8
#define DH    128
#define ROWS  (BATCH*NQ)   // 9216

// ---- async global->LDS, 16B per lane --------------------------------------
typedef const unsigned int __attribute__((address_space(1)))* gas_ptr;
typedef unsigned int __attribute__((address_space(3)))* las_ptr;

__device__ __forceinline__ void async16(const bf16* g, bf16* l) {
  __builtin_amdgcn_global_load_lds((gas_ptr)g, (las_ptr)l, 16, 0, 0);
}

// ---- f32 -> bf16 streaming convert (n % 1024 == 0) ------------------------
__global__ __launch_bounds__(256) void cvt_kernel(
    const float* __restrict__ s, bf16* __restrict__ d)
{
  const int i = (blockIdx.x * 256 + threadIdx.x) * 4;
  f32x4 v = *(const f32x4*)(s + i);
  bf16x4 o;
#pragma unroll
  for (int j = 0; j < 4; ++j) o[j] = (bf16)v[j];
  *(bf16x4*)(d + i) = o;
}

enum { MODE_BIAS = 0, MODE_GG = 1, MODE_GGACC = 2, MODE_GB = 3 };

// ===========================================================================
// gemm_256: 256x256 tile, BK=64, 8 waves (2Mx4N), per-wave 128x64 output.
// 4 phases per K-tile; B-frags read once (P0) and held in regs; staging of
// tile t+2 staggered across phases with a single vmcnt(6) per K-tile.
// Requires M%256==0, N%256==0, K%64==0, K>=128.
// ===========================================================================
template <int MODE, typename OutT>
__global__ __launch_bounds__(512, 2) void gemm_256(
    const bf16* __restrict__ A, const bf16* __restrict__ W,
    const float* __restrict__ bias, OutT* __restrict__ C,
    const float* __restrict__ gates, int M, int N, int K)
{
  __shared__ bf16 LDS[2 * 32768];   // per buf: A 16384 el + B 16384 el

  const int tid  = threadIdx.x;
  const int lane = tid & 63;
  const int w    = tid >> 6;        // 0..7
  const int w_m  = w >> 2;          // 0..1 -> 128-row half
  const int w_n  = w & 3;           // 0..3 -> 64-col quarter
  const int l15  = lane & 15;
  const int quad = lane >> 4;
  const int m0   = blockIdx.y * 256;
  const int n0   = blockIdx.x * 256;

  // ---- staging lambdas: one 64-row part (8KB), per-thread 16B.
  // LDS linear dest (gload_lds constraint); pre-swizzled global source:
  // slot s of row r holds global chunk s ^ (r&7).
  auto stA = [&](int buf, int rowOff, int kt) {
    const int r = rowOff + (tid >> 3);
    async16(A + (size_t)(m0 + r) * K + kt + (((tid & 7) ^ (r & 7)) << 3),
            LDS + buf * 32768 + r * 64 + ((tid & 7) << 3));
  };
  auto stB = [&](int buf, int rowOff, int kt) {
    const int r = rowOff + (tid >> 3);
    async16(W + (size_t)(n0 + r) * K + kt + (((tid & 7) ^ (r & 7)) << 3),
            LDS + buf * 32768 + 16384 + r * 64 + ((tid & 7) << 3));
  };

  // ---- fragment read offsets (swizzled, 0-conflict: proven round 9)
  const int aoff0 = ((0 + quad) ^ (l15 & 7)) * 8;   // k-half 0
  const int aoff1 = ((4 + quad) ^ (l15 & 7)) * 8;   // k-half 1
  const int arow  = w_m * 128 + l15;                 // + mi*16
  const int brow  = w_n * 64 + l15;                  // + ni*16

  f32x4 acc[8][4] = {};
  const int nt = K >> 6;

  // ---- prologue: tile0 full (8 loads) + tile1 {B-lo,B-hi,A.L1} (6 loads)
  stB(0, 0, 0);   stB(0, 64, 0);  stB(0, 128, 0); stB(0, 192, 0);
  stA(0, 0, 0);   stA(0, 64, 0);  stA(0, 128, 0); stA(0, 192, 0);
  stB(1, 0, 64);  stB(1, 64, 64); stB(1, 128, 64); stB(1, 192, 64);
  stA(1, 0, 64);  stA(1, 128, 64);
  asm volatile("s_waitcnt vmcnt(6)" ::: "memory");
  __builtin_amdgcn_sched_barrier(0);
  __builtin_amdgcn_s_barrier();

  for (int t = 0; t < nt; ++t) {
    const int cb = t & 1;
    const int nb = cb ^ 1;
    const bf16* Ab = LDS + cb * 32768;
    const bf16* Bb = Ab + 16384;
    const bool pf1 = (t + 1 < nt);
    const bool pf2 = (t + 2 < nt);
    const int kt1 = (t + 1) << 6;
    const int kt2 = (t + 2) << 6;

    bf16x8 bfr[4][2];
    bf16x8 af0, af1, af2, af3;

#define READ_A(MB)                                                         \
    af0 = *(const bf16x8*)(Ab + ((MB) * 16 + arow) * 64 + aoff0);          \
    af1 = *(const bf16x8*)(Ab + ((MB) * 16 + arow) * 64 + aoff1);          \
    af2 = *(const bf16x8*)(Ab + ((MB) * 16 + 16 + arow) * 64 + aoff0);     \
    af3 = *(const bf16x8*)(Ab + ((MB) * 16 + 16 + arow) * 64 + aoff1);

#define DO_MFMA(MB)                                                        \
    _Pragma("unroll")                                                      \
    for (int ni = 0; ni < 4; ++ni) {                                       \
      acc[MB][ni]     = __builtin_amdgcn_mfma_f32_16x16x32_bf16(           \
          af0, bfr[ni][0], acc[MB][ni], 0, 0, 0);                          \
      acc[MB][ni]     = __builtin_amdgcn_mfma_f32_16x16x32_bf16(           \
          af1, bfr[ni][1], acc[MB][ni], 0, 0, 0);                          \
      acc[MB + 1][ni] = __builtin_amdgcn_mfma_f32_16x16x32_bf16(           \
          af2, bfr[ni][0], acc[MB + 1][ni], 0, 0, 0);                      \
      acc[MB + 1][ni] = __builtin_amdgcn_mfma_f32_16x16x32_bf16(           \
          af3, bfr[ni][1], acc[MB + 1][ni], 0, 0, 0);                      \
    }

#define PHASE_SYNC                                                         \
    __builtin_amdgcn_s_barrier();                                          \
    asm volatile("s_waitcnt lgkmcnt(0)" ::: "memory");                     \
    __builtin_amdgcn_sched_barrier(0);

    // ---- P0: all B-frags + A mi{0,1}; stage A.L2(t+1)
#pragma unroll
    for (int ni = 0; ni < 4; ++ni) {
      bfr[ni][0] = *(const bf16x8*)(Bb + (brow + ni * 16) * 64 + aoff0);
      bfr[ni][1] = *(const bf16x8*)(Bb + (brow + ni * 16) * 64 + aoff1);
    }
    READ_A(0)
    if (pf1) { stA(nb, 64, kt1); stA(nb, 192, kt1); }
    PHASE_SYNC
    __builtin_amdgcn_s_setprio(1);
    DO_MFMA(0)
    __builtin_amdgcn_s_setprio(0);
    __builtin_amdgcn_s_barrier();

    // ---- P1: A mi{2,3}; stage B-lo(t+2)
    READ_A(2)
    if (pf2) { stB(cb, 0, kt2); stB(cb, 64, kt2); }
    PHASE_SYNC
    __builtin_amdgcn_s_setprio(1);
    DO_MFMA(2)
    __builtin_amdgcn_s_setprio(0);
    __builtin_amdgcn_s_barrier();

    // ---- P2: A mi{4,5}; stage B-hi(t+2)
    READ_A(4)
    if (pf2) { stB(cb, 128, kt2); stB(cb, 192, kt2); }
    PHASE_SYNC
    __builtin_amdgcn_s_setprio(1);
    DO_MFMA(4)
    __builtin_amdgcn_s_setprio(0);
    __builtin_amdgcn_s_barrier();

    // ---- P3: A mi{6,7}; stage A.L1(t+2); counted vmcnt (once per K-tile)
    READ_A(6)
    if (pf2) { stA(cb, 0, kt2); stA(cb, 128, kt2); }
    if (pf1) {
      if (pf2) { asm volatile("s_waitcnt vmcnt(6)" ::: "memory"); }
      else     { asm volatile("s_waitcnt vmcnt(0)" ::: "memory"); }
      __builtin_amdgcn_sched_barrier(0);
    }
    PHASE_SYNC
    __builtin_amdgcn_s_setprio(1);
    DO_MFMA(6)
    __builtin_amdgcn_s_setprio(0);
    __builtin_amdgcn_s_barrier();

#undef READ_A
#undef DO_MFMA
#undef PHASE_SYNC
  }

  // ---- epilogue: C/D layout col=lane&15, row=quad*4+r  (M%256==0: no clamp)
#pragma unroll
  for (int ni = 0; ni < 4; ++ni) {
    const int col = n0 + w_n * 64 + ni * 16 + l15;
    const float bv = bias[col];
#pragma unroll
    for (int mi = 0; mi < 8; ++mi) {
      const int rowb = m0 + w_m * 128 + mi * 16 + quad * 4;
#pragma unroll
      for (int r = 0; r < 4; ++r) {
        const int gr = rowb + r;
        const size_t idx = (size_t)gr * N + col;
        if (MODE == MODE_GB) {
          C[idx] = (OutT)(acc[mi][ni][r] +
                          (gates[gr * 2] + gates[gr * 2 + 1]) * bv);
        } else {
          float v = acc[mi][ni][r] + bv;
          if (MODE == MODE_GG || MODE == MODE_GGACC)
            v = 0.5f * v * (1.0f + erff(v * 0.70710678118654752f));
          if (MODE == MODE_GG)
            C[idx] = (OutT)(v * gates[gr * 2]);
          else if (MODE == MODE_GGACC)
            C[idx] = (OutT)((float)C[idx] + v * gates[gr * 2 + 1]);
          else
            C[idx] = (OutT)v;
        }
      }
    }
  }
}

// ===========================================================================
// gemm_bt: 128x128 tile, BK=64, XOR swizzle (round-9 verified, 833 TF).
// Used for the N=1024 projection GEMMs.
// ===========================================================================
template <int MODE, typename OutT>
__global__ __launch_bounds__(256) void gemm_bt(
    const bf16* __restrict__ A, const bf16* __restrict__ W,
    const float* __restrict__ bias, OutT* __restrict__ C,
    const float* __restrict__ gates, int M, int N, int K)
{
  __shared__ bf16 As[128 * 64];
  __shared__ bf16 Bs[128 * 64];

  const int tid  = threadIdx.x;
  const int lane = tid & 63;
  const int w    = tid >> 6;
  const int wm   = (w & 1) * 64;
  const int wn   = (w >> 1) * 64;
  const int l15  = lane & 15;
  const int quad = lane >> 4;
  const int m0   = blockIdx.y * 128;
  const int n0   = blockIdx.x * 128;

  f32x4 acc[4][4] = {};

  const int srow0  = tid >> 3;                       // 0..31
  const int schunk = (tid & 7) ^ (srow0 & 7);
  int arows[4], brows[4];
#pragma unroll
  for (int j = 0; j < 4; ++j) {
    int r = m0 + j * 32 + srow0; if (r > M - 1) r = M - 1;
    arows[j] = r;
    brows[j] = n0 + j * 32 + srow0;
  }
  const int kc = schunk * 8;
  bf16* lA = As + tid * 8;
  bf16* lB = Bs + tid * 8;

  const int axb  = (quad ^ (l15 & 7)) * 8;
  const int axb1 = axb ^ 32;

  for (int kt = 0; kt < K; kt += 64) {
#pragma unroll
    for (int j = 0; j < 4; ++j)
      async16(A + (size_t)arows[j] * K + kt + kc, lA + j * 2048);
#pragma unroll
    for (int j = 0; j < 4; ++j)
      async16(W + (size_t)brows[j] * K + kt + kc, lB + j * 2048);
    __syncthreads();

    bf16x8 af[4], bfr[4];
#pragma unroll
    for (int i = 0; i < 4; ++i)
      af[i] = *(const bf16x8*)(As + (wm + i * 16 + l15) * 64 + axb);
#pragma unroll
    for (int i = 0; i < 4; ++i)
      bfr[i] = *(const bf16x8*)(Bs + (wn + i * 16 + l15) * 64 + axb);
#pragma unroll
    for (int mi = 0; mi < 4; ++mi)
#pragma unroll
      for (int ni = 0; ni < 4; ++ni)
        acc[mi][ni] = __builtin_amdgcn_mfma_f32_16x16x32_bf16(
            af[mi], bfr[ni], acc[mi][ni], 0, 0, 0);
#pragma unroll
    for (int i = 0; i < 4; ++i)
      af[i] = *(const bf16x8*)(As + (wm + i * 16 + l15) * 64 + axb1);
#pragma unroll
    for (int i = 0; i < 4; ++i)
      bfr[i] = *(const bf16x8*)(Bs + (wn + i * 16 + l15) * 64 + axb1);
#pragma unroll
    for (int mi = 0; mi < 4; ++mi)
#pragma unroll
      for (int ni = 0; ni < 4; ++ni)
        acc[mi][ni] = __builtin_amdgcn_mfma_f32_16x16x32_bf16(
            af[mi], bfr[ni], acc[mi][ni], 0, 0, 0);
    __syncthreads();
  }

#pragma unroll
  for (int ni = 0; ni < 4; ++ni) {
    const int col = n0 + wn + ni * 16 + l15;
    const float bv = bias[col];
#pragma unroll
    for (int mi = 0; mi < 4; ++mi) {
      const int rowb = m0 + wm + mi * 16 + quad * 4;
#pragma unroll
      for (int r = 0; r < 4; ++r) {
        const int gr = rowb + r;
        if (gr < M) {
          const size_t idx = (size_t)gr * N + col;
          if (MODE == MODE_GB) {
            C[idx] = (OutT)(acc[mi][ni][r] +
                            (gates[gr * 2] + gates[gr * 2 + 1]) * bv);
          } else {
            float v = acc[mi][ni][r] + bv;
            if (MODE == MODE_GG || MODE == MODE_GGACC)
              v = 0.5f * v * (1.0f + erff(v * 0.70710678118654752f));
            if (MODE == MODE_GG)
              C[idx] = (OutT)(v * gates[gr * 2]);
            else if (MODE == MODE_GGACC)
              C[idx] = (OutT)((float)C[idx] + v * gates[gr * 2 + 1]);
            else
              C[idx] = (OutT)v;
          }
        }
      }
    }
  }
}

// ===========================================================================
// Flash attention: grid (9 q-tiles, 16 batch, 8 heads), 64 q-rows per block.
// ===========================================================================
__global__ __launch_bounds__(256) void attn_kernel(
    const bf16* __restrict__ qp, const bf16* __restrict__ kp,
    const bf16* __restrict__ vp, bf16* __restrict__ ctx)
{
  __shared__ bf16 Qs[64 * 128];
  __shared__ bf16 Ks[64 * 128];
  __shared__ bf16 Vt[128 * 64];  // [d][key]
  __shared__ bf16 Ps[64 * 64];

  const int qt = blockIdx.x, b = blockIdx.y, h = blockIdx.z;
  const int tid = threadIdx.x, lane = tid & 63, w = tid >> 6;
  const int l15 = lane & 15, quad = lane >> 4;
  const int q0 = qt * 64;

#pragma unroll
  for (int i = 0; i < 4; ++i) {
    const int c = i * 256 + tid;
    const int row = c >> 4, col = (c & 15) * 8;
    *(bf16x8*)(Qs + row * 128 + col) =
        *(const bf16x8*)(qp + (size_t)(q0 + row) * MM + h * DH + col);
  }

  float m_r[4], l_r[4];
  f32x4 accO[8] = {};
#pragma unroll
  for (int r = 0; r < 4; ++r) { m_r[r] = -1e30f; l_r[r] = 0.f; }

  const float scale = 0.08838834764831843f;  // 1/sqrt(128)

  for (int kt = 0; kt < 9; ++kt) {
    __syncthreads();
    const int kbase = b * NQ + kt * 64;
#pragma unroll
    for (int i = 0; i < 4; ++i) {
      const int c = i * 256 + tid;
      const int row = c >> 4, col = (c & 15) * 8;
      *(bf16x8*)(Ks + row * 128 + col) =
          *(const bf16x8*)(kp + (size_t)(kbase + row) * MM + h * DH + col);
      bf16x8 vv = *(const bf16x8*)(vp + (size_t)(kbase + row) * MM + h * DH + col);
#pragma unroll
      for (int j = 0; j < 8; ++j) Vt[(col + j) * 64 + row] = vv[j];
    }
    __syncthreads();

    f32x4 sacc[4] = {};
#pragma unroll
    for (int kcq = 0; kcq < 4; ++kcq) {
      bf16x8 aq = *(const bf16x8*)(Qs + (w * 16 + l15) * 128 + kcq * 32 + quad * 8);
#pragma unroll
      for (int ni = 0; ni < 4; ++ni) {
        bf16x8 bk = *(const bf16x8*)(Ks + (ni * 16 + l15) * 128 + kcq * 32 + quad * 8);
        sacc[ni] = __builtin_amdgcn_mfma_f32_16x16x32_bf16(aq, bk, sacc[ni], 0, 0, 0);
      }
    }
#pragma unroll
    for (int ni = 0; ni < 4; ++ni)
#pragma unroll
      for (int r = 0; r < 4; ++r) sacc[ni][r] *= scale;

    float p[4][4];
#pragma unroll
    for (int r = 0; r < 4; ++r) {
      float mx = fmaxf(fmaxf(sacc[0][r], sacc[1][r]), fmaxf(sacc[2][r], sacc[3][r]));
#pragma unroll
      for (int off = 8; off >= 1; off >>= 1) mx = fmaxf(mx, __shfl_xor(mx, off, 64));
      const float mnew = fmaxf(m_r[r], mx);
      const float al = expf(m_r[r] - mnew);
      float rs = 0.f;
#pragma unroll
      for (int ni = 0; ni < 4; ++ni) { p[ni][r] = expf(sacc[ni][r] - mnew); rs += p[ni][r]; }
#pragma unroll
      for (int off = 8; off >= 1; off >>= 1) rs += __shfl_xor(rs, off, 64);
      l_r[r] = l_r[r] * al + rs;
      m_r[r] = mnew;
#pragma unroll
      for (int ni2 = 0; ni2 < 8; ++ni2) accO[ni2][r] *= al;
    }

#pragma unroll
    for (int ni = 0; ni < 4; ++ni)
#pragma unroll
      for (int r = 0; r < 4; ++r)
        Ps[(w * 16 + quad * 4 + r) * 64 + ni * 16 + l15] = (bf16)p[ni][r];

#pragma unroll
    for (int kc2 = 0; kc2 < 2; ++kc2) {
      bf16x8 ap = *(const bf16x8*)(Ps + (w * 16 + l15) * 64 + kc2 * 32 + quad * 8);
#pragma unroll
      for (int ni2 = 0; ni2 < 8; ++ni2) {
        bf16x8 bv = *(const bf16x8*)(Vt + (ni2 * 16 + l15) * 64 + kc2 * 32 + quad * 8);
        accO[ni2] = __builtin_amdgcn_mfma_f32_16x16x32_bf16(ap, bv, accO[ni2], 0, 0, 0);
      }
    }
  }

#pragma unroll
  for (int r = 0; r < 4; ++r) {
    const float inv = 1.0f / l_r[r];
    const int qrow = q0 + w * 16 + quad * 4 + r;
#pragma unroll
    for (int ni2 = 0; ni2 < 8; ++ni2)
      ctx[(size_t)(b * NQ + qrow) * MM + h * DH + ni2 * 16 + l15] =
          (bf16)(accO[ni2][r] * inv);
  }
}

// ===========================================================================
// Fused x-row pass: LayerNorm(kv) + kin(+pos) + x_bf convert + gating.
// ===========================================================================
__global__ __launch_bounds__(256) void lnx_kernel(
    const float* __restrict__ x, const float* __restrict__ g,
    const float* __restrict__ bta, const float* __restrict__ pos,
    const float* __restrict__ wg, const float* __restrict__ wn,
    const float* __restrict__ noise,
    bf16* __restrict__ kv, bf16* __restrict__ kin,
    bf16* __restrict__ x_bf, float* __restrict__ gates)
{
  const int row = blockIdx.x, tid = threadIdx.x;
  f32x4 xv = *(const f32x4*)(x + (size_t)row * MM + tid * 4);

  float s = 0.f, ss = 0.f, a0 = 0.f, a1 = 0.f, c0 = 0.f, c1 = 0.f;
#pragma unroll
  for (int j = 0; j < 4; ++j) {
    const int c = tid * 4 + j;
    s  += xv[j];
    ss += xv[j] * xv[j];
    a0 += xv[j] * wg[c * 2];
    a1 += xv[j] * wg[c * 2 + 1];
    c0 += xv[j] * wn[c * 2];
    c1 += xv[j] * wn[c * 2 + 1];
  }

  {
    bf16x4 o;
#pragma unroll
    for (int j = 0; j < 4; ++j) o[j] = (bf16)xv[j];
    *(bf16x4*)(x_bf + (size_t)row * MM + tid * 4) = o;
  }

#pragma unroll
  for (int off = 32; off >= 1; off >>= 1) {
    s  += __shfl_xor(s,  off, 64);  ss += __shfl_xor(ss, off, 64);
    a0 += __shfl_xor(a0, off, 64);  a1 += __shfl_xor(a1, off, 64);
    c0 += __shfl_xor(c0, off, 64);  c1 += __shfl_xor(c1, off, 64);
  }
  __shared__ float red[24];
  const int w = tid >> 6;
  if ((tid & 63) == 0) {
    red[w * 6]     = s;  red[w * 6 + 1] = ss;
    red[w * 6 + 2] = a0; red[w * 6 + 3] = a1;
    red[w * 6 + 4] = c0; red[w * 6 + 5] = c1;
  }
  __syncthreads();
  s  = red[0] + red[6]  + red[12] + red[18];
  ss = red[1] + red[7]  + red[13] + red[19];

  const float mu   = s * (1.0f / MM);
  const float rsig = rsqrtf(ss * (1.0f / MM) - mu * mu + 1e-5f);
  const int prow = row % NQ;
#pragma unroll
  for (int j = 0; j < 4; ++j) {
    const int c = tid * 4 + j;
    const float y = (xv[j] - mu) * rsig * g[c] + bta[c];
    kv[(size_t)row * MM + c]  = (bf16)y;
    kin[(size_t)row * MM + c] = (bf16)(y + pos[(size_t)prow * MM + c]);
  }

  if (tid == 0) {
    a0 = red[2] + red[8]  + red[14] + red[20];
    a1 = red[3] + red[9]  + red[15] + red[21];
    c0 = red[4] + red[10] + red[16] + red[22];
    c1 = red[5] + red[11] + red[17] + red[23];
    const float sp0 = fmaxf(c0, 0.f) + log1pf(expf(-fabsf(c0)));
    const float sp1 = fmaxf(c1, 0.f) + log1pf(expf(-fabsf(c1)));
    const float l0 = a0 + noise[row * 2]     * (sp0 + 0.01f);
    const float l1 = a1 + noise[row * 2 + 1] * (sp1 + 0.01f);
    const float mx = fmaxf(l0, l1);
    const float e0 = expf(l0 - mx), e1 = expf(l1 - mx);
    const float inv = 1.0f / (e0 + e1);
    const float p0 = e0 * inv, p1 = e1 * inv;
    const float den = 1.0f / (p0 + p1 + 1e-6f);
    gates[row * 2]     = p0 * den;
    gates[row * 2 + 1] = p1 * den;
  }
}

__global__ __launch_bounds__(256) void ln_q_kernel(
    const float* __restrict__ query, const float* __restrict__ g,
    const float* __restrict__ bta, const float* __restrict__ pos,
    bf16* __restrict__ qout)
{
  const int row = blockIdx.x, tid = threadIdx.x;
  f32x4 xv = *(const f32x4*)(query + (size_t)row * MM + tid * 4);
  float s = 0.f, ss = 0.f;
#pragma unroll
  for (int j = 0; j < 4; ++j) { s += xv[j]; ss += xv[j] * xv[j]; }
#pragma unroll
  for (int off = 32; off >= 1; off >>= 1) { s += __shfl_xor(s, off, 64); ss += __shfl_xor(ss, off, 64); }
  __shared__ float red[8];
  const int w = tid >> 6;
  if ((tid & 63) == 0) { red[w] = s; red[4 + w] = ss; }
  __syncthreads();
  s  = red[0] + red[1] + red[2] + red[3];
  ss = red[4] + red[5] + red[6] + red[7];
  const float mu = s * (1.0f / MM);
  const float rsig = rsqrtf(ss * (1.0f / MM) - mu * mu + 1e-5f);
#pragma unroll
  for (int j = 0; j < 4; ++j) {
    const int c = tid * 4 + j;
    const float y = (xv[j] - mu) * rsig * g[c] + bta[c] + pos[(size_t)row * MM + c];
    qout[(size_t)row * MM + c] = (bf16)y;
  }
}

// ===========================================================================
extern "C" void kernel_launch(void* const* d_in, const int* in_sizes, int n_in,
                              void* d_out, int out_size, void* d_ws, size_t ws_size,
                              hipStream_t stream)
{
  const float* x       = (const float*)d_in[0];
  const float* noise   = (const float*)d_in[1];
  const float* W1      = (const float*)d_in[2];
  const float* b1      = (const float*)d_in[3];
  const float* W2      = (const float*)d_in[4];
  const float* b2      = (const float*)d_in[5];
  const float* query   = (const float*)d_in[6];
  const float* pos     = (const float*)d_in[7];
  const float* ln_q_g  = (const float*)d_in[8];
  const float* ln_q_b  = (const float*)d_in[9];
  const float* ln_kv_g = (const float*)d_in[10];
  const float* ln_kv_b = (const float*)d_in[11];
  const float* ipw     = (const float*)d_in[12];
  const float* ipb     = (const float*)d_in[13];
  const float* out_w   = (const float*)d_in[14];
  const float* out_b   = (const float*)d_in[15];
  const float* w_gate  = (const float*)d_in[16];
  const float* w_noise = (const float*)d_in[17];
  float* out = (float*)d_out;  // (16,576,4096) float32 = 150994944 B

  char* ws = (char*)d_ws;
  bf16*  kin   = (bf16*)(ws);
  bf16*  ctx   = kin;                              // after kin dead
  bf16*  kp    = (bf16*)(ws + 18874368);
  bf16*  vp    = (bf16*)(ws + 37748736);
  bf16*  qbuf  = (bf16*)(ws + 56623104);
  bf16*  qp    = (bf16*)(ws + 57802752);
  bf16*  ipwb  = (bf16*)(ws + 58982400);           // 3*1024*1024 bf16
  bf16*  outwb = (bf16*)(ws + 65273856);           // 1024*1024 bf16
  bf16*  h     = (bf16*)(ws);                      // after attention phase
  bf16*  x_bf  = (bf16*)(ws + 75497472);
  bf16*  W1b   = (bf16*)(ws + 94371840);
  bf16*  W2b   = (bf16*)(ws + 102760448);
  float* gates = (float*)(ws + 136314880);
  bf16*  kv       = (bf16*)d_out;                      // scratch, 18.9MB
  bf16*  attn_out = (bf16*)((char*)d_out + 18874368);  // scratch, 18.9MB

  // 1) weight converts + fused x pass (LN + x_bf + gating)
  cvt_kernel<<<4096,  256, 0, stream>>>(W1, W1b);
  cvt_kernel<<<16384, 256, 0, stream>>>(W2, W2b);
  cvt_kernel<<<3072,  256, 0, stream>>>(ipw,   ipwb);
  cvt_kernel<<<1024,  256, 0, stream>>>(out_w, outwb);
  lnx_kernel<<<ROWS, 256, 0, stream>>>(x, ln_kv_g, ln_kv_b, pos,
                                       w_gate, w_noise, noise,
                                       kv, kin, x_bf, gates);
  ln_q_kernel<<<NQ, 256, 0, stream>>>(query, ln_q_g, ln_q_b, pos, qbuf);

  // 2) attention chain
  gemm_bt<MODE_BIAS, bf16><<<dim3(8, 5),  256, 0, stream>>>(qbuf, ipwb, ipb, qp, nullptr, NQ, MM, MM);
  gemm_bt<MODE_BIAS, bf16><<<dim3(8, 72), 256, 0, stream>>>(kin, ipwb + (size_t)MM * MM, ipb + MM, kp, nullptr, ROWS, MM, MM);
  gemm_bt<MODE_BIAS, bf16><<<dim3(8, 72), 256, 0, stream>>>(kv, ipwb + (size_t)2 * MM * MM, ipb + 2 * MM, vp, nullptr, ROWS, MM, MM);

  attn_kernel<<<dim3(9, BATCH, HEADS), 256, 0, stream>>>(qp, kp, vp, ctx);

  gemm_bt<MODE_BIAS, bf16><<<dim3(8, 72), 256, 0, stream>>>(ctx, outwb, out_b, attn_out, nullptr, ROWS, MM, MM);

  // 3) combined expert branch on the 8-phase 256^2 kernel:
  //    h  = g0 * gelu(x@W1^T + b1)
  //    h += g1 * gelu(attn_out@W1^T + b1)
  //    out = h @ W2^T + (g0+g1)*b2
  gemm_256<MODE_GG,    bf16><<<dim3(16, 36), 512, 0, stream>>>(x_bf,     W1b, b1, h, gates, ROWS, HID, MM);
  gemm_256<MODE_GGACC, bf16><<<dim3(16, 36), 512, 0, stream>>>(attn_out, W1b, b1, h, gates, ROWS, HID, MM);
  gemm_256<MODE_GB,   float><<<dim3(16, 36), 512, 0, stream>>>(h,        W2b, b2, out, gates, ROWS, HID, HID);
}

// Round 11
// 1372.602 us; speedup vs baseline: 1.0057x; 1.0057x over previous
//
#include <hip/hip_runtime.h>
#include <hip/hip_bf16.h>
#include <cstdint>
#include <cstddef>

// Round 11: revert to round-9 engine (1335us verified best; gemm_256 deep
// pipeline measured 727 TF < gemm_bt's 833 TF — third deep-pipeline miss,
// abandoned). Single delta: attn_kernel Qs/Ks/Ps chunk-XOR swizzle
// (chunk ^= row&7 at write AND read) — removes the 16-way ds_read_b128
// bank conflicts on the QK and PV(P) paths (same involution that took the
// GEMM from 3.8e7 conflicts to 0 in round 9). Vt untouched (transpose
// write constraint; proper fix is ds_read_b64_tr_b16, not risked blind).

typedef __bf16 bf16;
typedef __bf16 bf16x4 __attribute__((ext_vector_type(4)));
typedef __bf16 bf16x8 __attribute__((ext_vector_type(8)));
typedef float  f32x4  __attribute__((ext_vector_type(4)));

#define BATCH 16
#define NQ    576
#define MM    1024
#define HID   4096
#define HEADS 8
#define DH    128
#define ROWS  (BATCH*NQ)   // 9216

// ---- async global->LDS, 16B per lane --------------------------------------
typedef const unsigned int __attribute__((address_space(1)))* gas_ptr;
typedef unsigned int __attribute__((address_space(3)))* las_ptr;

__device__ __forceinline__ void async16(const bf16* g, bf16* l) {
  __builtin_amdgcn_global_load_lds((gas_ptr)g, (las_ptr)l, 16, 0, 0);
}

// ---- f32 -> bf16 streaming convert (n % 1024 == 0) ------------------------
__global__ __launch_bounds__(256) void cvt_kernel(
    const float* __restrict__ s, bf16* __restrict__ d)
{
  const int i = (blockIdx.x * 256 + threadIdx.x) * 4;
  f32x4 v = *(const f32x4*)(s + i);
  bf16x4 o;
#pragma unroll
  for (int j = 0; j < 4; ++j) o[j] = (bf16)v[j];
  *(bf16x4*)(d + i) = o;
}

// ===========================================================================
// GEMM: C[M,N] = A[M,K] @ W[N,K]^T + bias[N], fused epilogues.
// 128x128 tile, BK=64, 4 waves (2x2), 4x4 MFMA 16x16x32, 2 k-halves/iter.
// LDS: row r = 8 chunks of 16B; slot s holds global chunk s ^ (r&7)
// (round-9 verified: SQ_LDS_BANK_CONFLICT == 0, 833 TF).
// NOTE (r3/r4/r10): deeper pipelines / bigger acc all measured SLOWER than
// this structure (657-727 TF). Do not re-roll without new evidence.
// NOTE (r7): do NOT XCD-swizzle blockIdx (natural map: XCD=n%8 -> 4MB
// B-set/XCD L2; swizzle doubled FETCH_SIZE).
// ===========================================================================
enum { MODE_BIAS = 0, MODE_GG = 1, MODE_GGACC = 2, MODE_GB = 3 };

template <int MODE, typename OutT>
__global__ __launch_bounds__(256) void gemm_bt(
    const bf16* __restrict__ A, const bf16* __restrict__ W,
    const float* __restrict__ bias, OutT* __restrict__ C,
    const float* __restrict__ gates, int M, int N, int K)
{
  __shared__ bf16 As[128 * 64];
  __shared__ bf16 Bs[128 * 64];

  const int tid  = threadIdx.x;
  const int lane = tid & 63;
  const int w    = tid >> 6;
  const int wm   = (w & 1) * 64;
  const int wn   = (w >> 1) * 64;
  const int l15  = lane & 15;
  const int quad = lane >> 4;
  const int m0   = blockIdx.y * 128;
  const int n0   = blockIdx.x * 128;

  f32x4 acc[4][4] = {};

  const int srow0  = tid >> 3;                       // 0..31
  const int schunk = (tid & 7) ^ (srow0 & 7);
  int arows[4], brows[4];
#pragma unroll
  for (int j = 0; j < 4; ++j) {
    int r = m0 + j * 32 + srow0; if (r > M - 1) r = M - 1;
    arows[j] = r;
    brows[j] = n0 + j * 32 + srow0;
  }
  const int kc = schunk * 8;
  bf16* lA = As + tid * 8;
  bf16* lB = Bs + tid * 8;

  const int axb  = (quad ^ (l15 & 7)) * 8;
  const int axb1 = axb ^ 32;

  for (int kt = 0; kt < K; kt += 64) {
#pragma unroll
    for (int j = 0; j < 4; ++j)
      async16(A + (size_t)arows[j] * K + kt + kc, lA + j * 2048);
#pragma unroll
    for (int j = 0; j < 4; ++j)
      async16(W + (size_t)brows[j] * K + kt + kc, lB + j * 2048);
    __syncthreads();

    bf16x8 af[4], bfr[4];
#pragma unroll
    for (int i = 0; i < 4; ++i)
      af[i] = *(const bf16x8*)(As + (wm + i * 16 + l15) * 64 + axb);
#pragma unroll
    for (int i = 0; i < 4; ++i)
      bfr[i] = *(const bf16x8*)(Bs + (wn + i * 16 + l15) * 64 + axb);
#pragma unroll
    for (int mi = 0; mi < 4; ++mi)
#pragma unroll
      for (int ni = 0; ni < 4; ++ni)
        acc[mi][ni] = __builtin_amdgcn_mfma_f32_16x16x32_bf16(
            af[mi], bfr[ni], acc[mi][ni], 0, 0, 0);
#pragma unroll
    for (int i = 0; i < 4; ++i)
      af[i] = *(const bf16x8*)(As + (wm + i * 16 + l15) * 64 + axb1);
#pragma unroll
    for (int i = 0; i < 4; ++i)
      bfr[i] = *(const bf16x8*)(Bs + (wn + i * 16 + l15) * 64 + axb1);
#pragma unroll
    for (int mi = 0; mi < 4; ++mi)
#pragma unroll
      for (int ni = 0; ni < 4; ++ni)
        acc[mi][ni] = __builtin_amdgcn_mfma_f32_16x16x32_bf16(
            af[mi], bfr[ni], acc[mi][ni], 0, 0, 0);
    __syncthreads();
  }

  // epilogue: C/D layout col=lane&15, row=quad*4+r
#pragma unroll
  for (int ni = 0; ni < 4; ++ni) {
    const int col = n0 + wn + ni * 16 + l15;
    const float bv = bias[col];
#pragma unroll
    for (int mi = 0; mi < 4; ++mi) {
      const int rowb = m0 + wm + mi * 16 + quad * 4;
#pragma unroll
      for (int r = 0; r < 4; ++r) {
        const int gr = rowb + r;
        if (gr < M) {
          const size_t idx = (size_t)gr * N + col;
          if (MODE == MODE_GB) {
            C[idx] = (OutT)(acc[mi][ni][r] +
                            (gates[gr * 2] + gates[gr * 2 + 1]) * bv);
          } else {
            float v = acc[mi][ni][r] + bv;
            if (MODE == MODE_GG || MODE == MODE_GGACC)
              v = 0.5f * v * (1.0f + erff(v * 0.70710678118654752f));
            if (MODE == MODE_GG)
              C[idx] = (OutT)(v * gates[gr * 2]);
            else if (MODE == MODE_GGACC)
              C[idx] = (OutT)((float)C[idx] + v * gates[gr * 2 + 1]);
            else
              C[idx] = (OutT)v;
          }
        }
      }
    }
  }
}

// ===========================================================================
// Flash attention: grid (9 q-tiles, 16 batch, 8 heads), 64 q-rows per block.
// Qs/Ks/Ps use the chunk-XOR swizzle (chunk ^= row&7 on 16B chunks, same
// involution at write and read) — kills the 16-way b128 read conflicts.
// Vt stays linear (transpose-write pattern defeats XOR/padding).
// ===========================================================================
__global__ __launch_bounds__(256) void attn_kernel(
    const bf16* __restrict__ qp, const bf16* __restrict__ kp,
    const bf16* __restrict__ vp, bf16* __restrict__ ctx)
{
  __shared__ bf16 Qs[64 * 128];
  __shared__ bf16 Ks[64 * 128];
  __shared__ bf16 Vt[128 * 64];  // [d][key]
  __shared__ bf16 Ps[64 * 64];

  const int qt = blockIdx.x, b = blockIdx.y, h = blockIdx.z;
  const int tid = threadIdx.x, lane = tid & 63, w = tid >> 6;
  const int l15 = lane & 15, quad = lane >> 4;
  const int q0 = qt * 64;
  const int sw = l15 & 7;  // row&7 for all fragment rows (row = X*16 + l15)

#pragma unroll
  for (int i = 0; i < 4; ++i) {
    const int c = i * 256 + tid;
    const int row = c >> 4, ch = c & 15;
    *(bf16x8*)(Qs + row * 128 + ((ch ^ (row & 7)) << 3)) =
        *(const bf16x8*)(qp + (size_t)(q0 + row) * MM + h * DH + ch * 8);
  }

  float m_r[4], l_r[4];
  f32x4 accO[8] = {};
#pragma unroll
  for (int r = 0; r < 4; ++r) { m_r[r] = -1e30f; l_r[r] = 0.f; }

  const float scale = 0.08838834764831843f;  // 1/sqrt(128)

  for (int kt = 0; kt < 9; ++kt) {
    __syncthreads();
    const int kbase = b * NQ + kt * 64;
#pragma unroll
    for (int i = 0; i < 4; ++i) {
      const int c = i * 256 + tid;
      const int row = c >> 4, ch = c & 15;
      *(bf16x8*)(Ks + row * 128 + ((ch ^ (row & 7)) << 3)) =
          *(const bf16x8*)(kp + (size_t)(kbase + row) * MM + h * DH + ch * 8);
      bf16x8 vv = *(const bf16x8*)(vp + (size_t)(kbase + row) * MM + h * DH + ch * 8);
#pragma unroll
      for (int j = 0; j < 8; ++j) Vt[(ch * 8 + j) * 64 + row] = vv[j];
    }
    __syncthreads();

    f32x4 sacc[4] = {};
#pragma unroll
    for (int kcq = 0; kcq < 4; ++kcq) {
      bf16x8 aq = *(const bf16x8*)(Qs + (w * 16 + l15) * 128 +
                                   (((kcq * 4 + quad) ^ sw) << 3));
#pragma unroll
      for (int ni = 0; ni < 4; ++ni) {
        bf16x8 bk = *(const bf16x8*)(Ks + (ni * 16 + l15) * 128 +
                                     (((kcq * 4 + quad) ^ sw) << 3));
        sacc[ni] = __builtin_amdgcn_mfma_f32_16x16x32_bf16(aq, bk, sacc[ni], 0, 0, 0);
      }
    }
#pragma unroll
    for (int ni = 0; ni < 4; ++ni)
#pragma unroll
      for (int r = 0; r < 4; ++r) sacc[ni][r] *= scale;

    float p[4][4];
#pragma unroll
    for (int r = 0; r < 4; ++r) {
      float mx = fmaxf(fmaxf(sacc[0][r], sacc[1][r]), fmaxf(sacc[2][r], sacc[3][r]));
#pragma unroll
      for (int off = 8; off >= 1; off >>= 1) mx = fmaxf(mx, __shfl_xor(mx, off, 64));
      const float mnew = fmaxf(m_r[r], mx);
      const float al = expf(m_r[r] - mnew);
      float rs = 0.f;
#pragma unroll
      for (int ni = 0; ni < 4; ++ni) { p[ni][r] = expf(sacc[ni][r] - mnew); rs += p[ni][r]; }
#pragma unroll
      for (int off = 8; off >= 1; off >>= 1) rs += __shfl_xor(rs, off, 64);
      l_r[r] = l_r[r] * al + rs;
      m_r[r] = mnew;
#pragma unroll
      for (int ni2 = 0; ni2 < 8; ++ni2) accO[ni2][r] *= al;
    }

    // P write: element (row, k) stored at chunk (k>>3) ^ (row&7)
#pragma unroll
    for (int ni = 0; ni < 4; ++ni)
#pragma unroll
      for (int r = 0; r < 4; ++r) {
        const int prow = w * 16 + quad * 4 + r;
        const int k = ni * 16 + l15;
        Ps[prow * 64 + (((k >> 3) ^ (prow & 7)) << 3) + (k & 7)] = (bf16)p[ni][r];
      }

#pragma unroll
    for (int kc2 = 0; kc2 < 2; ++kc2) {
      bf16x8 ap = *(const bf16x8*)(Ps + (w * 16 + l15) * 64 +
                                   (((kc2 * 4 + quad) ^ sw) << 3));
#pragma unroll
      for (int ni2 = 0; ni2 < 8; ++ni2) {
        bf16x8 bv = *(const bf16x8*)(Vt + (ni2 * 16 + l15) * 64 + kc2 * 32 + quad * 8);
        accO[ni2] = __builtin_amdgcn_mfma_f32_16x16x32_bf16(ap, bv, accO[ni2], 0, 0, 0);
      }
    }
  }

#pragma unroll
  for (int r = 0; r < 4; ++r) {
    const float inv = 1.0f / l_r[r];
    const int qrow = q0 + w * 16 + quad * 4 + r;
#pragma unroll
    for (int ni2 = 0; ni2 < 8; ++ni2)
      ctx[(size_t)(b * NQ + qrow) * MM + h * DH + ni2 * 16 + l15] =
          (bf16)(accO[ni2][r] * inv);
  }
}

// ===========================================================================
// Fused x-row pass: LayerNorm(kv) + kin(+pos) + x_bf convert + gating.
// ===========================================================================
__global__ __launch_bounds__(256) void lnx_kernel(
    const float* __restrict__ x, const float* __restrict__ g,
    const float* __restrict__ bta, const float* __restrict__ pos,
    const float* __restrict__ wg, const float* __restrict__ wn,
    const float* __restrict__ noise,
    bf16* __restrict__ kv, bf16* __restrict__ kin,
    bf16* __restrict__ x_bf, float* __restrict__ gates)
{
  const int row = blockIdx.x, tid = threadIdx.x;
  f32x4 xv = *(const f32x4*)(x + (size_t)row * MM + tid * 4);

  float s = 0.f, ss = 0.f, a0 = 0.f, a1 = 0.f, c0 = 0.f, c1 = 0.f;
#pragma unroll
  for (int j = 0; j < 4; ++j) {
    const int c = tid * 4 + j;
    s  += xv[j];
    ss += xv[j] * xv[j];
    a0 += xv[j] * wg[c * 2];
    a1 += xv[j] * wg[c * 2 + 1];
    c0 += xv[j] * wn[c * 2];
    c1 += xv[j] * wn[c * 2 + 1];
  }

  {
    bf16x4 o;
#pragma unroll
    for (int j = 0; j < 4; ++j) o[j] = (bf16)xv[j];
    *(bf16x4*)(x_bf + (size_t)row * MM + tid * 4) = o;
  }

#pragma unroll
  for (int off = 32; off >= 1; off >>= 1) {
    s  += __shfl_xor(s,  off, 64);  ss += __shfl_xor(ss, off, 64);
    a0 += __shfl_xor(a0, off, 64);  a1 += __shfl_xor(a1, off, 64);
    c0 += __shfl_xor(c0, off, 64);  c1 += __shfl_xor(c1, off, 64);
  }
  __shared__ float red[24];
  const int w = tid >> 6;
  if ((tid & 63) == 0) {
    red[w * 6]     = s;  red[w * 6 + 1] = ss;
    red[w * 6 + 2] = a0; red[w * 6 + 3] = a1;
    red[w * 6 + 4] = c0; red[w * 6 + 5] = c1;
  }
  __syncthreads();
  s  = red[0] + red[6]  + red[12] + red[18];
  ss = red[1] + red[7]  + red[13] + red[19];

  const float mu   = s * (1.0f / MM);
  const float rsig = rsqrtf(ss * (1.0f / MM) - mu * mu + 1e-5f);
  const int prow = row % NQ;
#pragma unroll
  for (int j = 0; j < 4; ++j) {
    const int c = tid * 4 + j;
    const float y = (xv[j] - mu) * rsig * g[c] + bta[c];
    kv[(size_t)row * MM + c]  = (bf16)y;
    kin[(size_t)row * MM + c] = (bf16)(y + pos[(size_t)prow * MM + c]);
  }

  if (tid == 0) {
    a0 = red[2] + red[8]  + red[14] + red[20];
    a1 = red[3] + red[9]  + red[15] + red[21];
    c0 = red[4] + red[10] + red[16] + red[22];
    c1 = red[5] + red[11] + red[17] + red[23];
    const float sp0 = fmaxf(c0, 0.f) + log1pf(expf(-fabsf(c0)));
    const float sp1 = fmaxf(c1, 0.f) + log1pf(expf(-fabsf(c1)));
    const float l0 = a0 + noise[row * 2]     * (sp0 + 0.01f);
    const float l1 = a1 + noise[row * 2 + 1] * (sp1 + 0.01f);
    const float mx = fmaxf(l0, l1);
    const float e0 = expf(l0 - mx), e1 = expf(l1 - mx);
    const float inv = 1.0f / (e0 + e1);
    const float p0 = e0 * inv, p1 = e1 * inv;
    const float den = 1.0f / (p0 + p1 + 1e-6f);
    gates[row * 2]     = p0 * den;
    gates[row * 2 + 1] = p1 * den;
  }
}

__global__ __launch_bounds__(256) void ln_q_kernel(
    const float* __restrict__ query, const float* __restrict__ g,
    const float* __restrict__ bta, const float* __restrict__ pos,
    bf16* __restrict__ qout)
{
  const int row = blockIdx.x, tid = threadIdx.x;
  f32x4 xv = *(const f32x4*)(query + (size_t)row * MM + tid * 4);
  float s = 0.f, ss = 0.f;
#pragma unroll
  for (int j = 0; j < 4; ++j) { s += xv[j]; ss += xv[j] * xv[j]; }
#pragma unroll
  for (int off = 32; off >= 1; off >>= 1) { s += __shfl_xor(s, off, 64); ss += __shfl_xor(ss, off, 64); }
  __shared__ float red[8];
  const int w = tid >> 6;
  if ((tid & 63) == 0) { red[w] = s; red[4 + w] = ss; }
  __syncthreads();
  s  = red[0] + red[1] + red[2] + red[3];
  ss = red[4] + red[5] + red[6] + red[7];
  const float mu = s * (1.0f / MM);
  const float rsig = rsqrtf(ss * (1.0f / MM) - mu * mu + 1e-5f);
#pragma unroll
  for (int j = 0; j < 4; ++j) {
    const int c = tid * 4 + j;
    const float y = (xv[j] - mu) * rsig * g[c] + bta[c] + pos[(size_t)row * MM + c];
    qout[(size_t)row * MM + c] = (bf16)y;
  }
}

// ===========================================================================
extern "C" void kernel_launch(void* const* d_in, const int* in_sizes, int n_in,
                              void* d_out, int out_size, void* d_ws, size_t ws_size,
                              hipStream_t stream)
{
  const float* x       = (const float*)d_in[0];
  const float* noise   = (const float*)d_in[1];
  const float* W1      = (const float*)d_in[2];
  const float* b1      = (const float*)d_in[3];
  const float* W2      = (const float*)d_in[4];
  const float* b2      = (const float*)d_in[5];
  const float* query   = (const float*)d_in[6];
  const float* pos     = (const float*)d_in[7];
  const float* ln_q_g  = (const float*)d_in[8];
  const float* ln_q_b  = (const float*)d_in[9];
  const float* ln_kv_g = (const float*)d_in[10];
  const float* ln_kv_b = (const float*)d_in[11];
  const float* ipw     = (const float*)d_in[12];
  const float* ipb     = (const float*)d_in[13];
  const float* out_w   = (const float*)d_in[14];
  const float* out_b   = (const float*)d_in[15];
  const float* w_gate  = (const float*)d_in[16];
  const float* w_noise = (const float*)d_in[17];
  float* out = (float*)d_out;  // (16,576,4096) float32 = 150994944 B

  char* ws = (char*)d_ws;
  bf16*  kin   = (bf16*)(ws);
  bf16*  ctx   = kin;                              // after kin dead
  bf16*  kp    = (bf16*)(ws + 18874368);
  bf16*  vp    = (bf16*)(ws + 37748736);
  bf16*  qbuf  = (bf16*)(ws + 56623104);
  bf16*  qp    = (bf16*)(ws + 57802752);
  bf16*  ipwb  = (bf16*)(ws + 58982400);           // 3*1024*1024 bf16
  bf16*  outwb = (bf16*)(ws + 65273856);           // 1024*1024 bf16
  bf16*  h     = (bf16*)(ws);                      // after attention phase
  bf16*  x_bf  = (bf16*)(ws + 75497472);
  bf16*  W1b   = (bf16*)(ws + 94371840);
  bf16*  W2b   = (bf16*)(ws + 102760448);
  float* gates = (float*)(ws + 136314880);
  bf16*  kv       = (bf16*)d_out;                      // scratch, 18.9MB
  bf16*  attn_out = (bf16*)((char*)d_out + 18874368);  // scratch, 18.9MB

  // 1) weight converts + fused x pass (LN + x_bf + gating)
  cvt_kernel<<<4096,  256, 0, stream>>>(W1, W1b);
  cvt_kernel<<<16384, 256, 0, stream>>>(W2, W2b);
  cvt_kernel<<<3072,  256, 0, stream>>>(ipw,   ipwb);
  cvt_kernel<<<1024,  256, 0, stream>>>(out_w, outwb);
  lnx_kernel<<<ROWS, 256, 0, stream>>>(x, ln_kv_g, ln_kv_b, pos,
                                       w_gate, w_noise, noise,
                                       kv, kin, x_bf, gates);
  ln_q_kernel<<<NQ, 256, 0, stream>>>(query, ln_q_g, ln_q_b, pos, qbuf);

  // 2) attention chain
  gemm_bt<MODE_BIAS, bf16><<<dim3(8, 5),  256, 0, stream>>>(qbuf, ipwb, ipb, qp, nullptr, NQ, MM, MM);
  gemm_bt<MODE_BIAS, bf16><<<dim3(8, 72), 256, 0, stream>>>(kin, ipwb + (size_t)MM * MM, ipb + MM, kp, nullptr, ROWS, MM, MM);
  gemm_bt<MODE_BIAS, bf16><<<dim3(8, 72), 256, 0, stream>>>(kv, ipwb + (size_t)2 * MM * MM, ipb + 2 * MM, vp, nullptr, ROWS, MM, MM);

  attn_kernel<<<dim3(9, BATCH, HEADS), 256, 0, stream>>>(qp, kp, vp, ctx);

  gemm_bt<MODE_BIAS, bf16><<<dim3(8, 72), 256, 0, stream>>>(ctx, outwb, out_b, attn_out, nullptr, ROWS, MM, MM);

  // 3) combined expert branch:
  //    h  = g0 * gelu(x@W1^T + b1)
  //    h += g1 * gelu(attn_out@W1^T + b1)
  //    out = h @ W2^T + (g0+g1)*b2        (single big W2 GEMM)
  gemm_bt<MODE_GG,    bf16><<<dim3(32, 72), 256, 0, stream>>>(x_bf,     W1b, b1, h, gates, ROWS, HID, MM);
  gemm_bt<MODE_GGACC, bf16><<<dim3(32, 72), 256, 0, stream>>>(attn_out, W1b, b1, h, gates, ROWS, HID, MM);
  gemm_bt<MODE_GB,   float><<<dim3(32, 72), 256, 0, stream>>>(h,        W2b, b2, out, gates, ROWS, HID, HID);
}

// Round 12
// 1236.919 us; speedup vs baseline: 1.1160x; 1.1097x over previous
//
#include <hip/hip_runtime.h>
#include <hip/hip_bf16.h>
#include <cstdint>
#include <cstddef>

// Round 12: attack the attention V-path. Bank math showed the in-kernel V
// transpose was a 32-way LDS write conflict re-paid 9x per (b,h), plus a
// 16-way Vt read. Fix: (1) one-time vtr_kernel transposes vp -> vT[b][d][key]
// (conflict paid once, coalesced output); (2) attn stages Q/K/V via
// global_load_lds with pre-swizzled global source + linear dest + XOR read
// (round-9-proven involution) -> all attn LDS traffic conflict-free.
// GEMM engine identical to round 9/11 (833 TF, 0 conflicts).

typedef __bf16 bf16;
typedef __bf16 bf16x4 __attribute__((ext_vector_type(4)));
typedef __bf16 bf16x8 __attribute__((ext_vector_type(8)));
typedef float  f32x4  __attribute__((ext_vector_type(4)));

#define BATCH 16
#define NQ    576
#define MM    1024
#define HID   4096
#define HEADS 8
#define DH    128
#define ROWS  (BATCH*NQ)   // 9216

// ---- async global->LDS, 16B per lane --------------------------------------
typedef const unsigned int __attribute__((address_space(1)))* gas_ptr;
typedef unsigned int __attribute__((address_space(3)))* las_ptr;

__device__ __forceinline__ void async16(const bf16* g, bf16* l) {
  __builtin_amdgcn_global_load_lds((gas_ptr)g, (las_ptr)l, 16, 0, 0);
}

// ---- f32 -> bf16 streaming convert (n % 1024 == 0) ------------------------
__global__ __launch_bounds__(256) void cvt_kernel(
    const float* __restrict__ s, bf16* __restrict__ d)
{
  const int i = (blockIdx.x * 256 + threadIdx.x) * 4;
  f32x4 v = *(const f32x4*)(s + i);
  bf16x4 o;
#pragma unroll
  for (int j = 0; j < 4; ++j) o[j] = (bf16)v[j];
  *(bf16x4*)(d + i) = o;
}

// ===========================================================================
// GEMM: C[M,N] = A[M,K] @ W[N,K]^T + bias[N], fused epilogues.
// 128x128 tile, BK=64, 4 waves (2x2), 4x4 MFMA 16x16x32, 2 k-halves/iter.
// LDS: row r = 8 chunks of 16B; slot s holds global chunk s ^ (r&7)
// (round-9 verified: SQ_LDS_BANK_CONFLICT == 0, 833 TF).
// NOTE (r3/r4/r10): deeper pipelines / bigger acc all measured SLOWER than
// this structure (657-727 TF). Do not re-roll without new evidence.
// NOTE (r7): do NOT XCD-swizzle blockIdx (natural map: XCD=n%8 -> 4MB
// B-set/XCD L2; swizzle doubled FETCH_SIZE).
// ===========================================================================
enum { MODE_BIAS = 0, MODE_GG = 1, MODE_GGACC = 2, MODE_GB = 3 };

template <int MODE, typename OutT>
__global__ __launch_bounds__(256) void gemm_bt(
    const bf16* __restrict__ A, const bf16* __restrict__ W,
    const float* __restrict__ bias, OutT* __restrict__ C,
    const float* __restrict__ gates, int M, int N, int K)
{
  __shared__ bf16 As[128 * 64];
  __shared__ bf16 Bs[128 * 64];

  const int tid  = threadIdx.x;
  const int lane = tid & 63;
  const int w    = tid >> 6;
  const int wm   = (w & 1) * 64;
  const int wn   = (w >> 1) * 64;
  const int l15  = lane & 15;
  const int quad = lane >> 4;
  const int m0   = blockIdx.y * 128;
  const int n0   = blockIdx.x * 128;

  f32x4 acc[4][4] = {};

  const int srow0  = tid >> 3;                       // 0..31
  const int schunk = (tid & 7) ^ (srow0 & 7);
  int arows[4], brows[4];
#pragma unroll
  for (int j = 0; j < 4; ++j) {
    int r = m0 + j * 32 + srow0; if (r > M - 1) r = M - 1;
    arows[j] = r;
    brows[j] = n0 + j * 32 + srow0;
  }
  const int kc = schunk * 8;
  bf16* lA = As + tid * 8;
  bf16* lB = Bs + tid * 8;

  const int axb  = (quad ^ (l15 & 7)) * 8;
  const int axb1 = axb ^ 32;

  for (int kt = 0; kt < K; kt += 64) {
#pragma unroll
    for (int j = 0; j < 4; ++j)
      async16(A + (size_t)arows[j] * K + kt + kc, lA + j * 2048);
#pragma unroll
    for (int j = 0; j < 4; ++j)
      async16(W + (size_t)brows[j] * K + kt + kc, lB + j * 2048);
    __syncthreads();

    bf16x8 af[4], bfr[4];
#pragma unroll
    for (int i = 0; i < 4; ++i)
      af[i] = *(const bf16x8*)(As + (wm + i * 16 + l15) * 64 + axb);
#pragma unroll
    for (int i = 0; i < 4; ++i)
      bfr[i] = *(const bf16x8*)(Bs + (wn + i * 16 + l15) * 64 + axb);
#pragma unroll
    for (int mi = 0; mi < 4; ++mi)
#pragma unroll
      for (int ni = 0; ni < 4; ++ni)
        acc[mi][ni] = __builtin_amdgcn_mfma_f32_16x16x32_bf16(
            af[mi], bfr[ni], acc[mi][ni], 0, 0, 0);
#pragma unroll
    for (int i = 0; i < 4; ++i)
      af[i] = *(const bf16x8*)(As + (wm + i * 16 + l15) * 64 + axb1);
#pragma unroll
    for (int i = 0; i < 4; ++i)
      bfr[i] = *(const bf16x8*)(Bs + (wn + i * 16 + l15) * 64 + axb1);
#pragma unroll
    for (int mi = 0; mi < 4; ++mi)
#pragma unroll
      for (int ni = 0; ni < 4; ++ni)
        acc[mi][ni] = __builtin_amdgcn_mfma_f32_16x16x32_bf16(
            af[mi], bfr[ni], acc[mi][ni], 0, 0, 0);
    __syncthreads();
  }

  // epilogue: C/D layout col=lane&15, row=quad*4+r
#pragma unroll
  for (int ni = 0; ni < 4; ++ni) {
    const int col = n0 + wn + ni * 16 + l15;
    const float bv = bias[col];
#pragma unroll
    for (int mi = 0; mi < 4; ++mi) {
      const int rowb = m0 + wm + mi * 16 + quad * 4;
#pragma unroll
      for (int r = 0; r < 4; ++r) {
        const int gr = rowb + r;
        if (gr < M) {
          const size_t idx = (size_t)gr * N + col;
          if (MODE == MODE_GB) {
            C[idx] = (OutT)(acc[mi][ni][r] +
                            (gates[gr * 2] + gates[gr * 2 + 1]) * bv);
          } else {
            float v = acc[mi][ni][r] + bv;
            if (MODE == MODE_GG || MODE == MODE_GGACC)
              v = 0.5f * v * (1.0f + erff(v * 0.70710678118654752f));
            if (MODE == MODE_GG)
              C[idx] = (OutT)(v * gates[gr * 2]);
            else if (MODE == MODE_GGACC)
              C[idx] = (OutT)((float)C[idx] + v * gates[gr * 2 + 1]);
            else
              C[idx] = (OutT)v;
          }
        }
      }
    }
  }
}

// ===========================================================================
// vtr_kernel: one-time V transpose vp[b*576+key][h*128+d] -> vT[(b*1024 +
// h*128+d)*576 + key]. LDS-tiled per (ktile,b,h): coalesced read, XOR-
// swizzled tile (slot s of d-row holds key-chunk s^(d&7)), coalesced write.
// ===========================================================================
__global__ __launch_bounds__(256) void vtr_kernel(
    const bf16* __restrict__ vp, bf16* __restrict__ vT)
{
  __shared__ bf16 T[128 * 64];
  const int kt = blockIdx.x, b = blockIdx.y, h = blockIdx.z;
  const int tid = threadIdx.x;
  const int k0 = kt * 64;

#pragma unroll
  for (int i = 0; i < 4; ++i) {
    const int c = i * 256 + tid;
    const int row = c >> 4, ch = c & 15;       // key-local, d-chunk
    bf16x8 v = *(const bf16x8*)(vp + (size_t)(b * NQ + k0 + row) * MM +
                                h * DH + ch * 8);
#pragma unroll
    for (int j = 0; j < 8; ++j) {
      const int d = ch * 8 + j;
      T[d * 64 + (((row >> 3) ^ (d & 7)) << 3) + (row & 7)] = v[j];
    }
  }
  __syncthreads();

#pragma unroll
  for (int i = 0; i < 4; ++i) {
    const int c = i * 256 + tid;
    const int drow = c >> 3, kch = c & 7;
    bf16x8 v = *(const bf16x8*)(T + drow * 64 + ((kch ^ (drow & 7)) << 3));
    *(bf16x8*)(vT + ((size_t)b * MM + h * DH + drow) * NQ + k0 + kch * 8) = v;
  }
}

// ===========================================================================
// Flash attention: grid (9 q-tiles, 16 batch, 8 heads), 64 q-rows per block.
// All tiles (Qs/Ks/Vt) staged via global_load_lds with pre-swizzled global
// source (slot s of row r holds chunk s^(r&7)) + XOR on ds_read -> zero
// bank conflicts. V comes pre-transposed from vT (vtr_kernel).
// ===========================================================================
__global__ __launch_bounds__(256) void attn_kernel(
    const bf16* __restrict__ qp, const bf16* __restrict__ kp,
    const bf16* __restrict__ vT, bf16* __restrict__ ctx)
{
  __shared__ bf16 Qs[64 * 128];
  __shared__ bf16 Ks[64 * 128];
  __shared__ bf16 Vt[128 * 64];  // [d][key], swizzled chunks
  __shared__ bf16 Ps[64 * 64];

  const int qt = blockIdx.x, b = blockIdx.y, h = blockIdx.z;
  const int tid = threadIdx.x, lane = tid & 63, w = tid >> 6;
  const int l15 = lane & 15, quad = lane >> 4;
  const int q0 = qt * 64;
  const int sw = l15 & 7;  // row&7 for all fragment rows (row = X*16 + l15)

  // Q stage (once): slot ch of row holds global chunk ch^(row&7)
#pragma unroll
  for (int i = 0; i < 4; ++i) {
    const int c = i * 256 + tid;
    const int row = c >> 4, ch = c & 15;
    async16(qp + (size_t)(q0 + row) * MM + h * DH + ((ch ^ (row & 7)) << 3),
            Qs + c * 8);
  }

  float m_r[4], l_r[4];
  f32x4 accO[8] = {};
#pragma unroll
  for (int r = 0; r < 4; ++r) { m_r[r] = -1e30f; l_r[r] = 0.f; }

  const float scale = 0.08838834764831843f;  // 1/sqrt(128)
  const size_t vbase = ((size_t)b * MM + h * DH) * NQ;

  for (int kt = 0; kt < 9; ++kt) {
    __syncthreads();
    const int kbase = b * NQ + kt * 64;
    const size_t vk = vbase + kt * 64;
#pragma unroll
    for (int i = 0; i < 4; ++i) {
      const int c = i * 256 + tid;
      const int row = c >> 4, ch = c & 15;
      async16(kp + (size_t)(kbase + row) * MM + h * DH + ((ch ^ (row & 7)) << 3),
              Ks + c * 8);
      const int drow = c >> 3, kch = c & 7;
      async16(vT + vk + (size_t)drow * NQ + ((kch ^ (drow & 7)) << 3),
              Vt + c * 8);
    }
    __syncthreads();

    f32x4 sacc[4] = {};
#pragma unroll
    for (int kcq = 0; kcq < 4; ++kcq) {
      bf16x8 aq = *(const bf16x8*)(Qs + (w * 16 + l15) * 128 +
                                   (((kcq * 4 + quad) ^ sw) << 3));
#pragma unroll
      for (int ni = 0; ni < 4; ++ni) {
        bf16x8 bk = *(const bf16x8*)(Ks + (ni * 16 + l15) * 128 +
                                     (((kcq * 4 + quad) ^ sw) << 3));
        sacc[ni] = __builtin_amdgcn_mfma_f32_16x16x32_bf16(aq, bk, sacc[ni], 0, 0, 0);
      }
    }
#pragma unroll
    for (int ni = 0; ni < 4; ++ni)
#pragma unroll
      for (int r = 0; r < 4; ++r) sacc[ni][r] *= scale;

    float p[4][4];
#pragma unroll
    for (int r = 0; r < 4; ++r) {
      float mx = fmaxf(fmaxf(sacc[0][r], sacc[1][r]), fmaxf(sacc[2][r], sacc[3][r]));
#pragma unroll
      for (int off = 8; off >= 1; off >>= 1) mx = fmaxf(mx, __shfl_xor(mx, off, 64));
      const float mnew = fmaxf(m_r[r], mx);
      const float al = expf(m_r[r] - mnew);
      float rs = 0.f;
#pragma unroll
      for (int ni = 0; ni < 4; ++ni) { p[ni][r] = expf(sacc[ni][r] - mnew); rs += p[ni][r]; }
#pragma unroll
      for (int off = 8; off >= 1; off >>= 1) rs += __shfl_xor(rs, off, 64);
      l_r[r] = l_r[r] * al + rs;
      m_r[r] = mnew;
#pragma unroll
      for (int ni2 = 0; ni2 < 8; ++ni2) accO[ni2][r] *= al;
    }

    // P write: element (row, k) stored at chunk (k>>3) ^ (row&7)
#pragma unroll
    for (int ni = 0; ni < 4; ++ni)
#pragma unroll
      for (int r = 0; r < 4; ++r) {
        const int prow = w * 16 + quad * 4 + r;
        const int k = ni * 16 + l15;
        Ps[prow * 64 + (((k >> 3) ^ (prow & 7)) << 3) + (k & 7)] = (bf16)p[ni][r];
      }

#pragma unroll
    for (int kc2 = 0; kc2 < 2; ++kc2) {
      bf16x8 ap = *(const bf16x8*)(Ps + (w * 16 + l15) * 64 +
                                   (((kc2 * 4 + quad) ^ sw) << 3));
#pragma unroll
      for (int ni2 = 0; ni2 < 8; ++ni2) {
        bf16x8 bv = *(const bf16x8*)(Vt + (ni2 * 16 + l15) * 64 +
                                     (((kc2 * 4 + quad) ^ sw) << 3));
        accO[ni2] = __builtin_amdgcn_mfma_f32_16x16x32_bf16(ap, bv, accO[ni2], 0, 0, 0);
      }
    }
  }

#pragma unroll
  for (int r = 0; r < 4; ++r) {
    const float inv = 1.0f / l_r[r];
    const int qrow = q0 + w * 16 + quad * 4 + r;
#pragma unroll
    for (int ni2 = 0; ni2 < 8; ++ni2)
      ctx[(size_t)(b * NQ + qrow) * MM + h * DH + ni2 * 16 + l15] =
          (bf16)(accO[ni2][r] * inv);
  }
}

// ===========================================================================
// Fused x-row pass: LayerNorm(kv) + kin(+pos) + x_bf convert + gating.
// ===========================================================================
__global__ __launch_bounds__(256) void lnx_kernel(
    const float* __restrict__ x, const float* __restrict__ g,
    const float* __restrict__ bta, const float* __restrict__ pos,
    const float* __restrict__ wg, const float* __restrict__ wn,
    const float* __restrict__ noise,
    bf16* __restrict__ kv, bf16* __restrict__ kin,
    bf16* __restrict__ x_bf, float* __restrict__ gates)
{
  const int row = blockIdx.x, tid = threadIdx.x;
  f32x4 xv = *(const f32x4*)(x + (size_t)row * MM + tid * 4);

  float s = 0.f, ss = 0.f, a0 = 0.f, a1 = 0.f, c0 = 0.f, c1 = 0.f;
#pragma unroll
  for (int j = 0; j < 4; ++j) {
    const int c = tid * 4 + j;
    s  += xv[j];
    ss += xv[j] * xv[j];
    a0 += xv[j] * wg[c * 2];
    a1 += xv[j] * wg[c * 2 + 1];
    c0 += xv[j] * wn[c * 2];
    c1 += xv[j] * wn[c * 2 + 1];
  }

  {
    bf16x4 o;
#pragma unroll
    for (int j = 0; j < 4; ++j) o[j] = (bf16)xv[j];
    *(bf16x4*)(x_bf + (size_t)row * MM + tid * 4) = o;
  }

#pragma unroll
  for (int off = 32; off >= 1; off >>= 1) {
    s  += __shfl_xor(s,  off, 64);  ss += __shfl_xor(ss, off, 64);
    a0 += __shfl_xor(a0, off, 64);  a1 += __shfl_xor(a1, off, 64);
    c0 += __shfl_xor(c0, off, 64);  c1 += __shfl_xor(c1, off, 64);
  }
  __shared__ float red[24];
  const int w = tid >> 6;
  if ((tid & 63) == 0) {
    red[w * 6]     = s;  red[w * 6 + 1] = ss;
    red[w * 6 + 2] = a0; red[w * 6 + 3] = a1;
    red[w * 6 + 4] = c0; red[w * 6 + 5] = c1;
  }
  __syncthreads();
  s  = red[0] + red[6]  + red[12] + red[18];
  ss = red[1] + red[7]  + red[13] + red[19];

  const float mu   = s * (1.0f / MM);
  const float rsig = rsqrtf(ss * (1.0f / MM) - mu * mu + 1e-5f);
  const int prow = row % NQ;
#pragma unroll
  for (int j = 0; j < 4; ++j) {
    const int c = tid * 4 + j;
    const float y = (xv[j] - mu) * rsig * g[c] + bta[c];
    kv[(size_t)row * MM + c]  = (bf16)y;
    kin[(size_t)row * MM + c] = (bf16)(y + pos[(size_t)prow * MM + c]);
  }

  if (tid == 0) {
    a0 = red[2] + red[8]  + red[14] + red[20];
    a1 = red[3] + red[9]  + red[15] + red[21];
    c0 = red[4] + red[10] + red[16] + red[22];
    c1 = red[5] + red[11] + red[17] + red[23];
    const float sp0 = fmaxf(c0, 0.f) + log1pf(expf(-fabsf(c0)));
    const float sp1 = fmaxf(c1, 0.f) + log1pf(expf(-fabsf(c1)));
    const float l0 = a0 + noise[row * 2]     * (sp0 + 0.01f);
    const float l1 = a1 + noise[row * 2 + 1] * (sp1 + 0.01f);
    const float mx = fmaxf(l0, l1);
    const float e0 = expf(l0 - mx), e1 = expf(l1 - mx);
    const float inv = 1.0f / (e0 + e1);
    const float p0 = e0 * inv, p1 = e1 * inv;
    const float den = 1.0f / (p0 + p1 + 1e-6f);
    gates[row * 2]     = p0 * den;
    gates[row * 2 + 1] = p1 * den;
  }
}

__global__ __launch_bounds__(256) void ln_q_kernel(
    const float* __restrict__ query, const float* __restrict__ g,
    const float* __restrict__ bta, const float* __restrict__ pos,
    bf16* __restrict__ qout)
{
  const int row = blockIdx.x, tid = threadIdx.x;
  f32x4 xv = *(const f32x4*)(query + (size_t)row * MM + tid * 4);
  float s = 0.f, ss = 0.f;
#pragma unroll
  for (int j = 0; j < 4; ++j) { s += xv[j]; ss += xv[j] * xv[j]; }
#pragma unroll
  for (int off = 32; off >= 1; off >>= 1) { s += __shfl_xor(s, off, 64); ss += __shfl_xor(ss, off, 64); }
  __shared__ float red[8];
  const int w = tid >> 6;
  if ((tid & 63) == 0) { red[w] = s; red[4 + w] = ss; }
  __syncthreads();
  s  = red[0] + red[1] + red[2] + red[3];
  ss = red[4] + red[5] + red[6] + red[7];
  const float mu = s * (1.0f / MM);
  const float rsig = rsqrtf(ss * (1.0f / MM) - mu * mu + 1e-5f);
#pragma unroll
  for (int j = 0; j < 4; ++j) {
    const int c = tid * 4 + j;
    const float y = (xv[j] - mu) * rsig * g[c] + bta[c] + pos[(size_t)row * MM + c];
    qout[(size_t)row * MM + c] = (bf16)y;
  }
}

// ===========================================================================
extern "C" void kernel_launch(void* const* d_in, const int* in_sizes, int n_in,
                              void* d_out, int out_size, void* d_ws, size_t ws_size,
                              hipStream_t stream)
{
  const float* x       = (const float*)d_in[0];
  const float* noise   = (const float*)d_in[1];
  const float* W1      = (const float*)d_in[2];
  const float* b1      = (const float*)d_in[3];
  const float* W2      = (const float*)d_in[4];
  const float* b2      = (const float*)d_in[5];
  const float* query   = (const float*)d_in[6];
  const float* pos     = (const float*)d_in[7];
  const float* ln_q_g  = (const float*)d_in[8];
  const float* ln_q_b  = (const float*)d_in[9];
  const float* ln_kv_g = (const float*)d_in[10];
  const float* ln_kv_b = (const float*)d_in[11];
  const float* ipw     = (const float*)d_in[12];
  const float* ipb     = (const float*)d_in[13];
  const float* out_w   = (const float*)d_in[14];
  const float* out_b   = (const float*)d_in[15];
  const float* w_gate  = (const float*)d_in[16];
  const float* w_noise = (const float*)d_in[17];
  float* out = (float*)d_out;  // (16,576,4096) float32 = 150994944 B

  // d_out scratch liveness: kv@0 (lnx -> vp-GEMM) -> vT@0 (vtr -> attn)
  // -> attn_out@18874368 (out-proj -> W1-GGACC) -> out (GB, last).
  char* ws = (char*)d_ws;
  bf16*  kin   = (bf16*)(ws);
  bf16*  ctx   = kin;                              // after kin dead
  bf16*  kp    = (bf16*)(ws + 18874368);
  bf16*  vp    = (bf16*)(ws + 37748736);
  bf16*  qbuf  = (bf16*)(ws + 56623104);
  bf16*  qp    = (bf16*)(ws + 57802752);
  bf16*  ipwb  = (bf16*)(ws + 58982400);           // 3*1024*1024 bf16
  bf16*  outwb = (bf16*)(ws + 65273856);           // 1024*1024 bf16
  bf16*  h     = (bf16*)(ws);                      // after attention phase
  bf16*  x_bf  = (bf16*)(ws + 75497472);
  bf16*  W1b   = (bf16*)(ws + 94371840);
  bf16*  W2b   = (bf16*)(ws + 102760448);
  float* gates = (float*)(ws + 136314880);
  bf16*  kv       = (bf16*)d_out;                      // scratch, 18.9MB
  bf16*  vT       = (bf16*)d_out;                      // reuses kv after dead
  bf16*  attn_out = (bf16*)((char*)d_out + 18874368);  // scratch, 18.9MB

  // 1) weight converts + fused x pass (LN + x_bf + gating)
  cvt_kernel<<<4096,  256, 0, stream>>>(W1, W1b);
  cvt_kernel<<<16384, 256, 0, stream>>>(W2, W2b);
  cvt_kernel<<<3072,  256, 0, stream>>>(ipw,   ipwb);
  cvt_kernel<<<1024,  256, 0, stream>>>(out_w, outwb);
  lnx_kernel<<<ROWS, 256, 0, stream>>>(x, ln_kv_g, ln_kv_b, pos,
                                       w_gate, w_noise, noise,
                                       kv, kin, x_bf, gates);
  ln_q_kernel<<<NQ, 256, 0, stream>>>(query, ln_q_g, ln_q_b, pos, qbuf);

  // 2) attention chain
  gemm_bt<MODE_BIAS, bf16><<<dim3(8, 5),  256, 0, stream>>>(qbuf, ipwb, ipb, qp, nullptr, NQ, MM, MM);
  gemm_bt<MODE_BIAS, bf16><<<dim3(8, 72), 256, 0, stream>>>(kin, ipwb + (size_t)MM * MM, ipb + MM, kp, nullptr, ROWS, MM, MM);
  gemm_bt<MODE_BIAS, bf16><<<dim3(8, 72), 256, 0, stream>>>(kv, ipwb + (size_t)2 * MM * MM, ipb + 2 * MM, vp, nullptr, ROWS, MM, MM);

  vtr_kernel<<<dim3(9, BATCH, HEADS), 256, 0, stream>>>(vp, vT);
  attn_kernel<<<dim3(9, BATCH, HEADS), 256, 0, stream>>>(qp, kp, vT, ctx);

  gemm_bt<MODE_BIAS, bf16><<<dim3(8, 72), 256, 0, stream>>>(ctx, outwb, out_b, attn_out, nullptr, ROWS, MM, MM);

  // 3) combined expert branch:
  //    h  = g0 * gelu(x@W1^T + b1)
  //    h += g1 * gelu(attn_out@W1^T + b1)
  //    out = h @ W2^T + (g0+g1)*b2        (single big W2 GEMM)
  gemm_bt<MODE_GG,    bf16><<<dim3(32, 72), 256, 0, stream>>>(x_bf,     W1b, b1, h, gates, ROWS, HID, MM);
  gemm_bt<MODE_GGACC, bf16><<<dim3(32, 72), 256, 0, stream>>>(attn_out, W1b, b1, h, gates, ROWS, HID, MM);
  gemm_bt<MODE_GB,   float><<<dim3(32, 72), 256, 0, stream>>>(h,        W2b, b2, out, gates, ROWS, HID, HID);
}